// Round 1
// baseline (166.140 us; speedup 1.0000x reference)
//
#include <hip/hip_runtime.h>
#include <stdint.h>

// ===========================================================================
// AnchorDataGenerator (Faster R-CNN anchor target layer), MI355X / gfx950
//
// Fixed problem size: scores (1,18,256,256) -> H=W=256, NUM_A=9, N=589824
// anchors; G=64 gt boxes; im_w=im_h=4096 read from device scalars.
//
// Outputs (concatenated flat in d_out, ALL written as float32):
//   labels: (1,1,2304,256)   = 589824   [idx t = a*65536 + h*256 + w]
//   adj:    (1,36,256,256)   = 2359296  [(a*4+j)*65536 + hw]
//   wts:    (1,36,256,256)   = 2359296
//
// RNG ASSUMPTION (flip if labels mismatch sparsely while adj passes):
//   jax_threefry_partitionable = True (modern JAX default):
//     split: key_i = threefry((0,42), (0, i))          -> kf=i0, kb=i1
//     bits(n) = o0 ^ o1 of threefry(key, (0, n)); mantissa = bits >> 9
//
// Subsample = keep 128 smallest (mantissa, anchor_index) per class, matching
// stable double-argsort semantics. Histogram on top-12 mantissa bits; the
// boundary bin is resolved exactly by O(C^2) ranking of its candidates.
// ===========================================================================

#define NUM_A 9
#define HW 65536
#define N_ANCH 589824
#define NG 64
#define CAPK 128u
#define NBIN 4096
#define CAND_CAP 8192

#define LAB_BG 0u
#define LAB_FG 1u
#define LAB_IGN 2u

// workspace layout (u32 units); total 630858 u32 = ~2.52 MB
#define OFF_GMAX 0
#define OFF_HF   64
#define OFF_HB   (OFF_HF + NBIN)          // 4160
#define OFF_CNTF (OFF_HB + NBIN)          // 8256
#define OFF_CNTB (OFF_CNTF + 1)           // 8257
#define OFF_SEL  (OFF_CNTB + 1)           // 8258: sel_f[4]={bin,below,need,K}, sel_b[4]
#define OFF_CANDF 8266                    // byte 33064, 8B aligned; u64 keys
#define OFF_CANDB (OFF_CANDF + 2*CAND_CAP)
#define OFF_LABM  (OFF_CANDB + 2*CAND_CAP)
#define INIT_WORDS OFF_CANDF

__constant__ float BA[NUM_A][4] = {
  { -84.f,  -40.f,  99.f,  55.f}, {-176.f,  -88.f, 191.f, 103.f},
  {-360.f, -184.f, 375.f, 199.f}, { -56.f,  -56.f,  71.f,  71.f},
  {-120.f, -120.f, 135.f, 135.f}, {-248.f, -248.f, 263.f, 263.f},
  { -36.f,  -80.f,  51.f,  95.f}, { -80.f, -168.f,  95.f, 183.f},
  {-168.f, -344.f, 183.f, 359.f}};

__host__ __device__ static inline void tf2x32(uint32_t k0, uint32_t k1,
                                              uint32_t x0, uint32_t x1,
                                              uint32_t* o0, uint32_t* o1) {
  const uint32_t ks2 = k0 ^ k1 ^ 0x1BD11BDAu;
#define TF_R(r) { x0 += x1; x1 = (x1 << (r)) | (x1 >> (32 - (r))); x1 ^= x0; }
  x0 += k0; x1 += k1;
  TF_R(13) TF_R(15) TF_R(26) TF_R(6)
  x0 += k1;  x1 += ks2 + 1u;
  TF_R(17) TF_R(29) TF_R(16) TF_R(24)
  x0 += ks2; x1 += k0 + 2u;
  TF_R(13) TF_R(15) TF_R(26) TF_R(6)
  x0 += k0;  x1 += k1 + 3u;
  TF_R(17) TF_R(29) TF_R(16) TF_R(24)
  x0 += k1;  x1 += ks2 + 4u;
  TF_R(13) TF_R(15) TF_R(26) TF_R(6)
  x0 += ks2; x1 += k0 + 5u;
#undef TF_R
  *o0 = x0; *o1 = x1;
}

__device__ static inline uint32_t mant_of(uint32_t k0, uint32_t k1, uint32_t n) {
  uint32_t o0, o1;
  tf2x32(k0, k1, 0u, n, &o0, &o1);   // partitionable: counter = (hi=0, lo=n)
  return (o0 ^ o1) >> 9;             // 23-bit mantissa; uniform = m * 2^-23
}

// IoU in the reference's exact fp32 op order (contraction OFF -> bit-exact
// and identical between k_gmax and k_main, required for the == g_max test).
__device__ static inline float iou1(float a0, float a1, float a2, float a3,
                                    float aarea, float g0, float g1, float g2,
                                    float g3, float garea) {
  #pragma clang fp contract(off)
  float ix1 = fmaxf(a0, g0);
  float iy1 = fmaxf(a1, g1);
  float ix2 = fminf(a2, g2);
  float iy2 = fminf(a3, g3);
  float iw = ix2 - ix1 + 1.0f;
  float ih = iy2 - iy1 + 1.0f;
  float inter = (iw > 0.0f && ih > 0.0f) ? iw * ih : 0.0f;
  float den = aarea + garea - inter;   // (a_area + g_area) - inter
  return inter / den;                  // IEEE-rounded div (no fast-math)
}

__global__ __launch_bounds__(256) void k_init(uint32_t* __restrict__ ws) {
  int i = blockIdx.x * 256 + threadIdx.x;
  if (i < INIT_WORDS) ws[i] = 0u;
}

// ---- per-gt max IoU over valid anchors -> ws[OFF_GMAX..64) as f32 bits ----
#define K1_APT 4
__global__ __launch_bounds__(256) void k_gmax(const float* __restrict__ gt,
                                              const int* __restrict__ imw_p,
                                              const int* __restrict__ imh_p,
                                              uint32_t* __restrict__ ws) {
  #pragma clang fp contract(off)
  __shared__ float sgt[NG][4];
  __shared__ float sga[NG];
  __shared__ uint32_t smax[NG];
  int tid = threadIdx.x;
  if (tid < NG) {
    float g0 = gt[tid*4+0], g1 = gt[tid*4+1], g2 = gt[tid*4+2], g3 = gt[tid*4+3];
    sgt[tid][0] = g0; sgt[tid][1] = g1; sgt[tid][2] = g2; sgt[tid][3] = g3;
    float gw = g2 - g0 + 1.0f, gh = g3 - g1 + 1.0f;
    sga[tid] = (gw > 0.0f && gh > 0.0f) ? gw * gh : 0.0f;
    smax[tid] = 0u;                       // bits of 0.0f; g_max >= 0 always
  }
  __syncthreads();
  float imw = (float)imw_p[0], imh = (float)imh_p[0];

  int base = (blockIdx.x * 256 + tid) * K1_APT;
  float A0[K1_APT], A1[K1_APT], A2[K1_APT], A3[K1_APT], AA[K1_APT];
  bool V[K1_APT];
  #pragma unroll
  for (int i = 0; i < K1_APT; i++) {
    int t = base + i;
    int a = t >> 16, hw = t & 65535, h = hw >> 8, w = hw & 255;
    float sx = (float)(w << 4), sy = (float)(h << 4);
    float x1 = BA[a][0] + sx, y1 = BA[a][1] + sy;
    float x2 = BA[a][2] + sx, y2 = BA[a][3] + sy;
    A0[i] = x1; A1[i] = y1; A2[i] = x2; A3[i] = y2;
    AA[i] = (x2 - x1 + 1.0f) * (y2 - y1 + 1.0f);
    V[i] = (x1 >= 0.0f) && (y1 >= 0.0f) && (x2 < imw) && (y2 < imh);
  }
  for (int g = 0; g < NG; g++) {
    float g0 = sgt[g][0], g1 = sgt[g][1], g2 = sgt[g][2], g3 = sgt[g][3];
    float ga = sga[g];
    float m = 0.0f;                       // 0-contribution is harmless: g_max>=0
    #pragma unroll
    for (int i = 0; i < K1_APT; i++) {
      float o = iou1(A0[i], A1[i], A2[i], A3[i], AA[i], g0, g1, g2, g3, ga);
      m = fmaxf(m, V[i] ? o : 0.0f);
    }
    #pragma unroll
    for (int s = 32; s >= 1; s >>= 1) m = fmaxf(m, __shfl_xor(m, s, 64));
    if ((tid & 63) == 0) atomicMax(&smax[g], __float_as_uint(m)); // >=0: uint order == float order
  }
  __syncthreads();
  if (tid < NG) atomicMax(&ws[OFF_GMAX + tid], smax[tid]);
}

// ---- main per-anchor pass: labels_pre, adj, RNG mantissa, histograms ----
__global__ __launch_bounds__(256) void k_main(const float* __restrict__ gt,
                                              const int* __restrict__ imw_p,
                                              const int* __restrict__ imh_p,
                                              float* __restrict__ out_adj,
                                              uint32_t* __restrict__ ws,
                                              uint32_t kf0, uint32_t kf1,
                                              uint32_t kb0, uint32_t kb1) {
  #pragma clang fp contract(off)
  __shared__ float sgt[NG][4];
  __shared__ float sga[NG];
  __shared__ float sgm[NG];
  __shared__ uint32_t shf[NBIN];
  __shared__ uint32_t shb[NBIN];
  int tid = threadIdx.x;
  for (int i = tid; i < NBIN; i += 256) { shf[i] = 0u; shb[i] = 0u; }
  if (tid < NG) {
    float g0 = gt[tid*4+0], g1 = gt[tid*4+1], g2 = gt[tid*4+2], g3 = gt[tid*4+3];
    sgt[tid][0] = g0; sgt[tid][1] = g1; sgt[tid][2] = g2; sgt[tid][3] = g3;
    float gw = g2 - g0 + 1.0f, gh = g3 - g1 + 1.0f;
    sga[tid] = (gw > 0.0f && gh > 0.0f) ? gw * gh : 0.0f;
    sgm[tid] = __uint_as_float(ws[OFF_GMAX + tid]);
  }
  __syncthreads();
  float imw = (float)imw_p[0], imh = (float)imh_p[0];

  int t = blockIdx.x * 256 + tid;       // output-major: a = t>>16 (wave-uniform)
  int a = t >> 16, hw = t & 65535, h = hw >> 8, w = hw & 255;
  float sx = (float)(w << 4), sy = (float)(h << 4);
  float A0 = BA[a][0] + sx, A1 = BA[a][1] + sy;
  float A2 = BA[a][2] + sx, A3 = BA[a][3] + sy;
  float aw = A2 - A0 + 1.0f, ah = A3 - A1 + 1.0f;
  float aarea = aw * ah;
  bool valid = (A0 >= 0.0f) && (A1 >= 0.0f) && (A2 < imw) && (A3 < imh);

  float amax = -1.0f;
  int bestg = 0;
  bool anyfg = false;
  for (int g = 0; g < NG; g++) {
    float o = iou1(A0, A1, A2, A3, aarea,
                   sgt[g][0], sgt[g][1], sgt[g][2], sgt[g][3], sga[g]);
    if (o > amax) { amax = o; bestg = g; }   // first-max tie-break == argmax
    anyfg |= (o == sgm[g]);
  }
  anyfg = anyfg && valid;

  uint32_t lab;
  if (!valid)                         lab = LAB_IGN;
  else if (anyfg || amax >= 0.7f)     lab = LAB_FG;
  else if (amax < 0.3f)               lab = LAB_BG;
  else                                lab = LAB_IGN;

  float adj0 = 0.f, adj1 = 0.f, adj2 = 0.f, adj3 = 0.f;
  if (valid) {
    float G0 = sgt[bestg][0], G1 = sgt[bestg][1];
    float G2 = sgt[bestg][2], G3 = sgt[bestg][3];
    float ax = (A2 + A0) * 0.5f, ay = (A3 + A1) * 0.5f;
    float gwm = G2 - G0 + 1.0f, ghm = G3 - G1 + 1.0f;
    float gx = (G2 + G0) * 0.5f, gy = (G3 + G1) * 0.5f;
    adj0 = (gx - ax) / aw;
    adj1 = (gy - ay) / ah;
    adj2 = logf(gwm / aw);
    adj3 = logf(ghm / ah);
  }
  int c4 = a * 4;
  out_adj[(c4 + 0) * HW + hw] = adj0;
  out_adj[(c4 + 1) * HW + hw] = adj1;
  out_adj[(c4 + 2) * HW + hw] = adj2;
  out_adj[(c4 + 3) * HW + hw] = adj3;

  uint32_t m = 0u;
  uint32_t n = (uint32_t)(hw * 9 + a);  // ORIGINAL anchor index: argsort tie-break
  if (lab == LAB_FG) { m = mant_of(kf0, kf1, n); atomicAdd(&shf[m >> 11], 1u); }
  else if (lab == LAB_BG) { m = mant_of(kb0, kb1, n); atomicAdd(&shb[m >> 11], 1u); }
  ws[OFF_LABM + t] = (lab << 24) | m;

  __syncthreads();
  for (int i = tid; i < NBIN; i += 256) {
    uint32_t v = shf[i]; if (v) atomicAdd(&ws[OFF_HF + i], v);
    v = shb[i];          if (v) atomicAdd(&ws[OFF_HB + i], v);
  }
}

// ---- find boundary bin per class: keep K=min(total,128) smallest ----
__global__ __launch_bounds__(256) void k_select(uint32_t* __restrict__ ws) {
  int cls = blockIdx.x;
  const uint32_t* hist = ws + (cls == 0 ? OFF_HF : OFF_HB);
  uint32_t* sel = ws + OFF_SEL + cls * 4;
  __shared__ uint32_t pre[256];
  int tid = threadIdx.x;
  uint32_t loc[16];
  uint32_t s = 0;
  #pragma unroll
  for (int j = 0; j < 16; j++) { loc[j] = hist[tid * 16 + j]; s += loc[j]; }
  pre[tid] = s; __syncthreads();
  for (int off = 1; off < 256; off <<= 1) {
    uint32_t v = (tid >= off) ? pre[tid - off] : 0u;
    __syncthreads();
    pre[tid] += v;
    __syncthreads();
  }
  uint32_t total = pre[255];
  uint32_t K = total < CAPK ? total : CAPK;
  if (tid == 0) {
    sel[3] = K;
    if (K == 0u) { sel[0] = 0xFFFFFFFFu; sel[1] = 0u; sel[2] = 0u; }
  }
  if (K > 0u) {
    uint32_t myCum = pre[tid];
    uint32_t prevCum = (tid == 0) ? 0u : pre[tid - 1];
    if (myCum >= K && prevCum < K) {      // exactly one thread
      uint32_t cum = prevCum;
      int b = tid * 16;
      for (int j = 0; j < 16; j++) {
        if (cum + loc[j] >= K) { b = tid * 16 + j; break; }
        cum += loc[j];
      }
      sel[0] = (uint32_t)b;   // boundary bin
      sel[1] = cum;           // kept below boundary
      sel[2] = K - cum;       // needed from boundary bin
    }
  }
}

// ---- emit labels + wts; boundary-bin anchors -> candidate lists ----
__global__ __launch_bounds__(256) void k_emit(float* __restrict__ out_lab,
                                              float* __restrict__ out_wts,
                                              uint32_t* __restrict__ ws) {
  int t = blockIdx.x * 256 + threadIdx.x;
  uint32_t lm = ws[OFF_LABM + t];
  uint32_t lab = lm >> 24;
  uint32_t m = lm & 0x7FFFFFu;
  uint32_t Kf = ws[OFF_SEL + 3], Kb = ws[OFF_SEL + 7];
  float inv = 1.0f / (float)(Kf + Kb);   // 1/num_ni, fp32 div like reference
  int a = t >> 16, hw = t & 65535;
  uint32_t n = (uint32_t)(hw * 9 + a);

  float outv = 2.0f, wv = 0.0f;
  if (lab == LAB_FG) {
    uint32_t b = m >> 11, bf = ws[OFF_SEL + 0];
    if (b < bf) { outv = 1.0f; wv = inv; }
    else if (b == bf) {
      uint32_t idx = atomicAdd(&ws[OFF_CNTF], 1u);
      if (idx < CAND_CAP)
        ((uint64_t*)(ws + OFF_CANDF))[idx] = ((uint64_t)m << 20) | (uint64_t)n;
      // provisional IGN; k_fixup promotes kept ones
    }
  } else if (lab == LAB_BG) {
    uint32_t b = m >> 11, bb = ws[OFF_SEL + 4];
    if (b < bb) { outv = 0.0f; }
    else if (b == bb) {
      uint32_t idx = atomicAdd(&ws[OFF_CNTB], 1u);
      if (idx < CAND_CAP)
        ((uint64_t*)(ws + OFF_CANDB))[idx] = ((uint64_t)m << 20) | (uint64_t)n;
    }
  }
  out_lab[t] = outv;
  int c4 = a * 4;
  out_wts[(c4 + 0) * HW + hw] = wv;
  out_wts[(c4 + 1) * HW + hw] = wv;
  out_wts[(c4 + 2) * HW + hw] = wv;
  out_wts[(c4 + 3) * HW + hw] = wv;
}

// ---- rank boundary candidates by (mantissa, index); promote rank < need ----
__global__ __launch_bounds__(256) void k_fixup(float* __restrict__ out_lab,
                                               float* __restrict__ out_wts,
                                               uint32_t* __restrict__ ws) {
  int cls = blockIdx.x;
  uint32_t cnt = ws[cls == 0 ? OFF_CNTF : OFF_CNTB];
  uint32_t C = cnt < CAND_CAP ? cnt : CAND_CAP;
  uint32_t need = ws[OFF_SEL + cls * 4 + 2];
  uint32_t Kf = ws[OFF_SEL + 3], Kb = ws[OFF_SEL + 7];
  float inv = 1.0f / (float)(Kf + Kb);
  const uint64_t* cand =
      (const uint64_t*)(ws + (cls == 0 ? OFF_CANDF : OFF_CANDB));
  for (uint32_t i = threadIdx.x; i < C; i += 256) {
    uint64_t k = cand[i];
    uint32_t r = 0;
    for (uint32_t j = 0; j < C; j++) r += (cand[j] < k) ? 1u : 0u;
    if (r < need) {                      // keys unique -> exactly `need` kept
      uint32_t n = (uint32_t)(k & 0xFFFFFu);
      uint32_t a = n % 9u, hw = n / 9u;
      uint32_t t = a * HW + hw;
      if (cls == 0) {
        out_lab[t] = 1.0f;
        #pragma unroll
        for (int j = 0; j < 4; j++) out_wts[(a * 4 + j) * HW + hw] = inv;
      } else {
        out_lab[t] = 0.0f;
      }
    }
  }
}

extern "C" void kernel_launch(void* const* d_in, const int* in_sizes, int n_in,
                              void* d_out, int out_size, void* d_ws,
                              size_t ws_size, hipStream_t stream) {
  const float* gt  = (const float*)d_in[1];
  const int*   imw = (const int*)d_in[2];
  const int*   imh = (const int*)d_in[3];
  float* out      = (float*)d_out;
  float* out_lab  = out;                   // 589824
  float* out_adj  = out + N_ANCH;          // 4*589824
  float* out_wts  = out + 5 * N_ANCH;      // 4*589824
  uint32_t* ws = (uint32_t*)d_ws;          // needs ~2.52 MB

  // JAX: kf, kb = split(key(42)) under threefry_partitionable=True
  uint32_t kf0, kf1, kb0, kb1;
  tf2x32(0u, 42u, 0u, 0u, &kf0, &kf1);
  tf2x32(0u, 42u, 0u, 1u, &kb0, &kb1);

  hipLaunchKernelGGL(k_init, dim3((INIT_WORDS + 255) / 256), dim3(256), 0,
                     stream, ws);
  hipLaunchKernelGGL(k_gmax, dim3(N_ANCH / (256 * K1_APT)), dim3(256), 0,
                     stream, gt, imw, imh, ws);
  hipLaunchKernelGGL(k_main, dim3(N_ANCH / 256), dim3(256), 0, stream, gt, imw,
                     imh, out_adj, ws, kf0, kf1, kb0, kb1);
  hipLaunchKernelGGL(k_select, dim3(2), dim3(256), 0, stream, ws);
  hipLaunchKernelGGL(k_emit, dim3(N_ANCH / 256), dim3(256), 0, stream, out_lab,
                     out_wts, ws);
  hipLaunchKernelGGL(k_fixup, dim3(2), dim3(256), 0, stream, out_lab, out_wts,
                     ws);
}

// Round 2
// 132.095 us; speedup vs baseline: 1.2577x; 1.2577x over previous
//
#include <hip/hip_runtime.h>
#include <stdint.h>

// ===========================================================================
// AnchorDataGenerator (Faster R-CNN anchor target layer), MI355X / gfx950
// Round 2: exploit sparsity of anchor-gt overlaps.
//  - k_gmax: per-gt windowed scan (~12k anchors/gt instead of 589k) + zeroes
//    the histogram region (k_init folded in).
//  - k_main: block-uniform y-overlap ballot prunes gt loop 64 -> ~8; per-wave
//    __any(iw>0) prunes the IEEE divide further. Bit-exact IoU preserved.
// 5 launches: k_gmax, k_main, k_select, k_emit, k_fixup.
// ===========================================================================

#define NUM_A 9
#define HW 65536
#define N_ANCH 589824
#define NG 64
#define CAPK 128u
#define NBIN 2048
#define BIN_SHIFT 12
#define CAND_CAP 4096

#define LAB_BG 0u
#define LAB_FG 1u
#define LAB_IGN 2u

// workspace layout (u32 units); total 610572 u32 ~= 2.44 MB
#define OFF_GMAX4 0                       // 64 gts x 4 slices, plain-stored
#define OFF_HF    256
#define OFF_HB    (OFF_HF + NBIN)         // 2304
#define OFF_CNTF  (OFF_HB + NBIN)         // 4352
#define OFF_CNTB  (OFF_CNTF + 1)          // 4353
#define OFF_SEL   (OFF_CNTB + 1)          // 4354..4361: {bin,below,need,K} x2
#define OFF_CANDF 4364                    // byte 17456, 8B aligned; u64 keys
#define OFF_CANDB (OFF_CANDF + 2*CAND_CAP)
#define OFF_LABM  (OFF_CANDB + 2*CAND_CAP)   // 20748
#define ZERO_BEG  OFF_HF
#define ZERO_END  (OFF_SEL + 8)           // 4362

__constant__ float BA[NUM_A][4] = {
  { -84.f,  -40.f,  99.f,  55.f}, {-176.f,  -88.f, 191.f, 103.f},
  {-360.f, -184.f, 375.f, 199.f}, { -56.f,  -56.f,  71.f,  71.f},
  {-120.f, -120.f, 135.f, 135.f}, {-248.f, -248.f, 263.f, 263.f},
  { -36.f,  -80.f,  51.f,  95.f}, { -80.f, -168.f,  95.f, 183.f},
  {-168.f, -344.f, 183.f, 359.f}};

__host__ __device__ static inline void tf2x32(uint32_t k0, uint32_t k1,
                                              uint32_t x0, uint32_t x1,
                                              uint32_t* o0, uint32_t* o1) {
  const uint32_t ks2 = k0 ^ k1 ^ 0x1BD11BDAu;
#define TF_R(r) { x0 += x1; x1 = (x1 << (r)) | (x1 >> (32 - (r))); x1 ^= x0; }
  x0 += k0; x1 += k1;
  TF_R(13) TF_R(15) TF_R(26) TF_R(6)
  x0 += k1;  x1 += ks2 + 1u;
  TF_R(17) TF_R(29) TF_R(16) TF_R(24)
  x0 += ks2; x1 += k0 + 2u;
  TF_R(13) TF_R(15) TF_R(26) TF_R(6)
  x0 += k0;  x1 += k1 + 3u;
  TF_R(17) TF_R(29) TF_R(16) TF_R(24)
  x0 += k1;  x1 += ks2 + 4u;
  TF_R(13) TF_R(15) TF_R(26) TF_R(6)
  x0 += ks2; x1 += k0 + 5u;
#undef TF_R
  *o0 = x0; *o1 = x1;
}

__device__ static inline uint32_t mant_of(uint32_t k0, uint32_t k1, uint32_t n) {
  uint32_t o0, o1;
  tf2x32(k0, k1, 0u, n, &o0, &o1);   // partitionable: counter = (hi=0, lo=n)
  return (o0 ^ o1) >> 9;             // 23-bit mantissa
}

// IoU in the reference's exact fp32 op order (contraction OFF -> bit-exact
// and identical between k_gmax and k_main, required for the == g_max test).
__device__ static inline float iou1(float a0, float a1, float a2, float a3,
                                    float aarea, float g0, float g1, float g2,
                                    float g3, float garea) {
  #pragma clang fp contract(off)
  float ix1 = fmaxf(a0, g0);
  float iy1 = fmaxf(a1, g1);
  float ix2 = fminf(a2, g2);
  float iy2 = fminf(a3, g3);
  float iw = ix2 - ix1 + 1.0f;
  float ih = iy2 - iy1 + 1.0f;
  float inter = (iw > 0.0f && ih > 0.0f) ? iw * ih : 0.0f;
  float den = aarea + garea - inter;
  return inter / den;                  // IEEE-rounded div
}

// ---- per-gt windowed max IoU; also zeroes histogram/counter region --------
__global__ __launch_bounds__(256) void k_gmax(const float* __restrict__ gt,
                                              const int* __restrict__ imw_p,
                                              const int* __restrict__ imh_p,
                                              uint32_t* __restrict__ ws) {
  #pragma clang fp contract(off)
  int tid = threadIdx.x;
  int b = blockIdx.x;
  // folded k_init: 256 blocks x 17 words cover [ZERO_BEG, ZERO_BEG+4352)
  {
    int base = ZERO_BEG + b * 17;
    #pragma unroll
    for (int i = 0; i < 17; i++)
      if (tid == 0 && base + i < ZERO_END) ws[base + i] = 0u;
  }
  int g = b >> 2, sl = b & 3;
  float g0 = gt[g*4+0], g1 = gt[g*4+1], g2 = gt[g*4+2], g3 = gt[g*4+3];
  float gw = g2 - g0 + 1.0f, gh = g3 - g1 + 1.0f;
  float ga = (gw > 0.0f && gh > 0.0f) ? gw * gh : 0.0f;
  float imw = (float)imw_p[0], imh = (float)imh_p[0];

  float mx = 0.0f;   // g_max >= 0 always (some valid anchor has ovl >= 0)
  for (int a = 0; a < NUM_A; a++) {
    float b0 = BA[a][0], b1 = BA[a][1], b2 = BA[a][2], b3 = BA[a][3];
    int wlo = max(0,   (int)floorf((g0 - 1.0f - b2) * 0.0625f));
    int whi = min(255, (int)ceilf ((g2 + 1.0f - b0) * 0.0625f));
    int hlo = max(0,   (int)floorf((g1 - 1.0f - b3) * 0.0625f));
    int hhi = min(255, (int)ceilf ((g3 + 1.0f - b1) * 0.0625f));
    int wx = whi - wlo + 1, wy = hhi - hlo + 1;
    if (wx <= 0 || wy <= 0) continue;
    int tot = wx * wy;
    for (int idx = sl * 256 + tid; idx < tot; idx += 1024) {
      int h = hlo + idx / wx, w = wlo + idx % wx;
      float sx = (float)(w << 4), sy = (float)(h << 4);
      float x1 = b0 + sx, y1 = b1 + sy, x2 = b2 + sx, y2 = b3 + sy;
      float aw = x2 - x1 + 1.0f, ah = y2 - y1 + 1.0f;
      float aarea = aw * ah;
      bool vld = (x1 >= 0.0f) && (y1 >= 0.0f) && (x2 < imw) && (y2 < imh);
      float o = iou1(x1, y1, x2, y2, aarea, g0, g1, g2, g3, ga);
      if (vld) mx = fmaxf(mx, o);
    }
  }
  #pragma unroll
  for (int s = 32; s >= 1; s >>= 1) mx = fmaxf(mx, __shfl_xor(mx, s, 64));
  __shared__ float wmax[4];
  if ((tid & 63) == 0) wmax[tid >> 6] = mx;
  __syncthreads();
  if (tid == 0) {
    float m = fmaxf(fmaxf(wmax[0], wmax[1]), fmaxf(wmax[2], wmax[3]));
    ws[OFF_GMAX4 + g * 4 + sl] = __float_as_uint(m);
  }
}

// ---- main per-anchor pass: labels_pre, adj, RNG mantissa, histograms ------
__global__ __launch_bounds__(256) void k_main(const float* __restrict__ gt,
                                              const int* __restrict__ imw_p,
                                              const int* __restrict__ imh_p,
                                              float* __restrict__ out_adj,
                                              uint32_t* __restrict__ ws,
                                              uint32_t kf0, uint32_t kf1,
                                              uint32_t kb0, uint32_t kb1) {
  #pragma clang fp contract(off)
  __shared__ float sg0[NG], sg1[NG], sg2[NG], sg3[NG], sga[NG], sgm[NG];
  __shared__ uint32_t sh[2 * NBIN];
  __shared__ unsigned long long sYMask;
  __shared__ int sAnyZero;
  int tid = threadIdx.x;
  for (int i = tid; i < 2 * NBIN; i += 256) sh[i] = 0u;

  // block-uniform anchor type / row
  int t0 = blockIdx.x * 256;
  int aU = t0 >> 16, hU = (t0 & 65535) >> 8;
  float syU = (float)(hU << 4);
  float A1 = BA[aU][1] + syU, A3 = BA[aU][3] + syU;

  if (tid == 0) sAnyZero = 0;
  if (tid < NG) {
    float g0 = gt[tid*4+0], g1 = gt[tid*4+1], g2 = gt[tid*4+2], g3 = gt[tid*4+3];
    sg0[tid] = g0; sg1[tid] = g1; sg2[tid] = g2; sg3[tid] = g3;
    float gw = g2 - g0 + 1.0f, gh = g3 - g1 + 1.0f;
    sga[tid] = (gw > 0.0f && gh > 0.0f) ? gw * gh : 0.0f;
    uint32_t m01 = max(ws[OFF_GMAX4 + tid*4 + 0], ws[OFF_GMAX4 + tid*4 + 1]);
    uint32_t m23 = max(ws[OFF_GMAX4 + tid*4 + 2], ws[OFF_GMAX4 + tid*4 + 3]);
    uint32_t mm = max(m01, m23);
    sgm[tid] = __uint_as_float(mm);
    if (mm == 0u) atomicOr(&sAnyZero, 1);        // degenerate g_max == 0
    // block-uniform y-overlap test for gt = lane (wave 0 only)
    float ih = fminf(A3, g3) - fmaxf(A1, g1) + 1.0f;
    unsigned long long msk = __ballot(ih > 0.0f);
    if (tid == 0) sYMask = msk;
  }
  __syncthreads();
  float imw = (float)imw_p[0], imh = (float)imh_p[0];

  int t = t0 + tid;
  int a = aU, hw = t & 65535, w = hw & 255;
  float sx = (float)(w << 4);
  float A0 = BA[a][0] + sx, A2 = BA[a][2] + sx;
  float aw = A2 - A0 + 1.0f, ah = A3 - A1 + 1.0f;
  float aarea = aw * ah;
  bool valid = (A0 >= 0.0f) && (A1 >= 0.0f) && (A2 < imw) && (A3 < imh);

  float amax = 0.0f;       // rows of all-zero ovl: a_max=0, argmax=0
  int bestg = 0;
  bool anyfg = false;
  unsigned long long msk = sYMask;
  while (msk) {            // ascending g order -> first-max argmax semantics
    int g = __ffsll(msk) - 1;
    msk &= msk - 1;
    float ix1 = fmaxf(A0, sg0[g]);
    float ix2 = fminf(A2, sg2[g]);
    float iw = ix2 - ix1 + 1.0f;
    if (!__any(iw > 0.0f)) continue;
    float iy1 = fmaxf(A1, sg1[g]);
    float iy2 = fminf(A3, sg3[g]);
    float ih = iy2 - iy1 + 1.0f;          // > 0 for whole block by mask
    float inter = (iw > 0.0f) ? iw * ih : 0.0f;
    float den = aarea + sga[g] - inter;
    float o = inter / den;                // IEEE
    if (o > amax) { amax = o; bestg = g; }
    anyfg |= (o == sgm[g]);
  }
  anyfg = (anyfg || (sAnyZero != 0)) && valid;

  uint32_t lab;
  if (!valid)                         lab = LAB_IGN;
  else if (anyfg || amax >= 0.7f)     lab = LAB_FG;
  else if (amax < 0.3f)               lab = LAB_BG;
  else                                lab = LAB_IGN;

  float adj0 = 0.f, adj1 = 0.f, adj2 = 0.f, adj3 = 0.f;
  if (valid) {
    float G0 = sg0[bestg], G1 = sg1[bestg], G2 = sg2[bestg], G3 = sg3[bestg];
    float ax = (A2 + A0) * 0.5f, ay = (A3 + A1) * 0.5f;
    float gwm = G2 - G0 + 1.0f, ghm = G3 - G1 + 1.0f;
    float gx = (G2 + G0) * 0.5f, gy = (G3 + G1) * 0.5f;
    adj0 = (gx - ax) / aw;
    adj1 = (gy - ay) / ah;
    adj2 = logf(gwm / aw);
    adj3 = logf(ghm / ah);
  }
  int c4 = a * 4;
  out_adj[(c4 + 0) * HW + hw] = adj0;
  out_adj[(c4 + 1) * HW + hw] = adj1;
  out_adj[(c4 + 2) * HW + hw] = adj2;
  out_adj[(c4 + 3) * HW + hw] = adj3;

  uint32_t m = 0u;
  uint32_t n = (uint32_t)(hw * 9 + a);  // ORIGINAL anchor index: tie-break key
  if (lab != LAB_IGN) {
    uint32_t kk0 = (lab == LAB_FG) ? kf0 : kb0;
    uint32_t kk1 = (lab == LAB_FG) ? kf1 : kb1;
    m = mant_of(kk0, kk1, n);
    atomicAdd(&sh[((lab == LAB_FG) ? 0 : NBIN) + (m >> BIN_SHIFT)], 1u);
  }
  ws[OFF_LABM + t] = (lab << 24) | m;

  __syncthreads();
  for (int i = tid; i < 2 * NBIN; i += 256) {
    uint32_t v = sh[i];
    if (v) atomicAdd(&ws[OFF_HF + i], v);   // OFF_HB contiguous after OFF_HF
  }
}

// ---- find boundary bin per class: keep K=min(total,128) smallest ----------
__global__ __launch_bounds__(256) void k_select(uint32_t* __restrict__ ws) {
  int cls = blockIdx.x;
  const uint32_t* hist = ws + (cls == 0 ? OFF_HF : OFF_HB);
  uint32_t* sel = ws + OFF_SEL + cls * 4;
  __shared__ uint32_t pre[256];
  int tid = threadIdx.x;
  uint32_t loc[8];
  uint32_t s = 0;
  #pragma unroll
  for (int j = 0; j < 8; j++) { loc[j] = hist[tid * 8 + j]; s += loc[j]; }
  pre[tid] = s; __syncthreads();
  for (int off = 1; off < 256; off <<= 1) {
    uint32_t v = (tid >= off) ? pre[tid - off] : 0u;
    __syncthreads();
    pre[tid] += v;
    __syncthreads();
  }
  uint32_t total = pre[255];
  uint32_t K = total < CAPK ? total : CAPK;
  if (tid == 0) {
    sel[3] = K;
    if (K == 0u) { sel[0] = 0xFFFFFFFFu; sel[1] = 0u; sel[2] = 0u; }
  }
  if (K > 0u) {
    uint32_t myCum = pre[tid];
    uint32_t prevCum = (tid == 0) ? 0u : pre[tid - 1];
    if (myCum >= K && prevCum < K) {      // exactly one thread
      uint32_t cum = prevCum;
      int b = tid * 8;
      for (int j = 0; j < 8; j++) {
        if (cum + loc[j] >= K) { b = tid * 8 + j; break; }
        cum += loc[j];
      }
      sel[0] = (uint32_t)b;
      sel[1] = cum;
      sel[2] = K - cum;
    }
  }
}

// ---- emit labels + wts; boundary-bin anchors -> candidate lists -----------
__global__ __launch_bounds__(256) void k_emit(float* __restrict__ out_lab,
                                              float* __restrict__ out_wts,
                                              uint32_t* __restrict__ ws) {
  int t = blockIdx.x * 256 + threadIdx.x;
  uint32_t lm = ws[OFF_LABM + t];
  uint32_t lab = lm >> 24;
  uint32_t m = lm & 0x7FFFFFu;
  uint32_t Kf = ws[OFF_SEL + 3], Kb = ws[OFF_SEL + 7];
  float inv = 1.0f / (float)(Kf + Kb);   // 1/num_ni
  int a = t >> 16, hw = t & 65535;
  uint32_t n = (uint32_t)(hw * 9 + a);

  float outv = 2.0f, wv = 0.0f;
  if (lab == LAB_FG) {
    uint32_t b = m >> BIN_SHIFT, bf = ws[OFF_SEL + 0];
    if (b < bf) { outv = 1.0f; wv = inv; }
    else if (b == bf) {
      uint32_t idx = atomicAdd(&ws[OFF_CNTF], 1u);
      if (idx < CAND_CAP)
        ((uint64_t*)(ws + OFF_CANDF))[idx] = ((uint64_t)m << 20) | (uint64_t)n;
    }
  } else if (lab == LAB_BG) {
    uint32_t b = m >> BIN_SHIFT, bb = ws[OFF_SEL + 4];
    if (b < bb) { outv = 0.0f; }
    else if (b == bb) {
      uint32_t idx = atomicAdd(&ws[OFF_CNTB], 1u);
      if (idx < CAND_CAP)
        ((uint64_t*)(ws + OFF_CANDB))[idx] = ((uint64_t)m << 20) | (uint64_t)n;
    }
  }
  out_lab[t] = outv;
  int c4 = a * 4;
  out_wts[(c4 + 0) * HW + hw] = wv;
  out_wts[(c4 + 1) * HW + hw] = wv;
  out_wts[(c4 + 2) * HW + hw] = wv;
  out_wts[(c4 + 3) * HW + hw] = wv;
}

// ---- rank boundary candidates by (mantissa, index); promote rank < need ---
__global__ __launch_bounds__(256) void k_fixup(float* __restrict__ out_lab,
                                               float* __restrict__ out_wts,
                                               uint32_t* __restrict__ ws) {
  int cls = blockIdx.x;
  uint32_t cnt = ws[cls == 0 ? OFF_CNTF : OFF_CNTB];
  uint32_t C = cnt < CAND_CAP ? cnt : CAND_CAP;
  uint32_t need = ws[OFF_SEL + cls * 4 + 2];
  uint32_t Kf = ws[OFF_SEL + 3], Kb = ws[OFF_SEL + 7];
  float inv = 1.0f / (float)(Kf + Kb);
  const uint64_t* cand =
      (const uint64_t*)(ws + (cls == 0 ? OFF_CANDF : OFF_CANDB));
  for (uint32_t i = threadIdx.x; i < C; i += 256) {
    uint64_t k = cand[i];
    uint32_t r = 0;
    for (uint32_t j = 0; j < C; j++) r += (cand[j] < k) ? 1u : 0u;
    if (r < need) {                      // keys unique -> exactly `need` kept
      uint32_t n = (uint32_t)(k & 0xFFFFFu);
      uint32_t a = n % 9u, hw = n / 9u;
      uint32_t t = a * HW + hw;
      if (cls == 0) {
        out_lab[t] = 1.0f;
        #pragma unroll
        for (int j = 0; j < 4; j++) out_wts[(a * 4 + j) * HW + hw] = inv;
      } else {
        out_lab[t] = 0.0f;
      }
    }
  }
}

extern "C" void kernel_launch(void* const* d_in, const int* in_sizes, int n_in,
                              void* d_out, int out_size, void* d_ws,
                              size_t ws_size, hipStream_t stream) {
  const float* gt  = (const float*)d_in[1];
  const int*   imw = (const int*)d_in[2];
  const int*   imh = (const int*)d_in[3];
  float* out      = (float*)d_out;
  float* out_lab  = out;                   // 589824
  float* out_adj  = out + N_ANCH;          // 4*589824
  float* out_wts  = out + 5 * N_ANCH;      // 4*589824
  uint32_t* ws = (uint32_t*)d_ws;          // ~2.44 MB used

  uint32_t kf0, kf1, kb0, kb1;
  tf2x32(0u, 42u, 0u, 0u, &kf0, &kf1);
  tf2x32(0u, 42u, 0u, 1u, &kb0, &kb1);

  hipLaunchKernelGGL(k_gmax, dim3(NG * 4), dim3(256), 0, stream, gt, imw, imh,
                     ws);
  hipLaunchKernelGGL(k_main, dim3(N_ANCH / 256), dim3(256), 0, stream, gt, imw,
                     imh, out_adj, ws, kf0, kf1, kb0, kb1);
  hipLaunchKernelGGL(k_select, dim3(2), dim3(256), 0, stream, ws);
  hipLaunchKernelGGL(k_emit, dim3(N_ANCH / 256), dim3(256), 0, stream, out_lab,
                     out_wts, ws);
  hipLaunchKernelGGL(k_fixup, dim3(2), dim3(256), 0, stream, out_lab, out_wts,
                     ws);
}

// Round 3
// 102.553 us; speedup vs baseline: 1.6200x; 1.2881x over previous
//
#include <hip/hip_runtime.h>
#include <stdint.h>

// ===========================================================================
// AnchorDataGenerator (Faster R-CNN anchor target layer), MI355X / gfx950
// Round 3: ILP + fewer dispatches.
//  - k_gmax: 512 blocks (8 slices/gt), windowed; also zeroes hist/ctr region.
//  - k_main: 576 blocks, 4 anchors/thread (one anchor-type x 4 rows per
//    block; lane = w). iw shared across rows, ih lane-uniform. Last block
//    (done-counter) computes the subsample boundary (select) in-kernel,
//    reading the global histogram with device-scope atomic loads.
//  - k_emit: labels/wts + boundary candidate push (plain stores; next kernel
//    boundary makes them coherent).
//  - k_fixup: 2 blocks, candidates staged in LDS, O(C^2) exact ranking.
// All IoU math bit-exact vs reference (contract off, IEEE div, same order).
// ===========================================================================

#define NUM_A 9
#define HW 65536
#define N_ANCH 589824
#define NG 64
#define CAPK 128u
#define NBIN 2048
#define BIN_SHIFT 12
#define CAND_CAP 4096

#define LAB_BG 0u
#define LAB_FG 1u
#define LAB_IGN 2u

// workspace layout (u32 units); total ~610832 u32 ~= 2.44 MB
#define OFF_GMAX8 0                        // 64 gts x 8 slices
#define OFF_HF    512
#define OFF_HB    (OFF_HF + NBIN)          // 2560
#define OFF_CNTF  (OFF_HF + 2*NBIN)        // 4608
#define OFF_CNTB  (OFF_CNTF + 1)           // 4609
#define OFF_DONE2 (OFF_CNTF + 2)           // 4610
#define OFF_SEL   (OFF_CNTF + 4)           // 4612..4619: {bin,below,need,K} x2
#define OFF_CANDF 4620                     // byte 18480, 8B aligned; u64 keys
#define OFF_CANDB (OFF_CANDF + 2*CAND_CAP) // 12812
#define OFF_LABM  (OFF_CANDB + 2*CAND_CAP) // 21004
#define ZERO_BEG  OFF_HF
#define ZERO_END  OFF_CANDF
#define NZ        (ZERO_END - ZERO_BEG)    // 4108 words

__constant__ float BA[NUM_A][4] = {
  { -84.f,  -40.f,  99.f,  55.f}, {-176.f,  -88.f, 191.f, 103.f},
  {-360.f, -184.f, 375.f, 199.f}, { -56.f,  -56.f,  71.f,  71.f},
  {-120.f, -120.f, 135.f, 135.f}, {-248.f, -248.f, 263.f, 263.f},
  { -36.f,  -80.f,  51.f,  95.f}, { -80.f, -168.f,  95.f, 183.f},
  {-168.f, -344.f, 183.f, 359.f}};

__host__ __device__ static inline void tf2x32(uint32_t k0, uint32_t k1,
                                              uint32_t x0, uint32_t x1,
                                              uint32_t* o0, uint32_t* o1) {
  const uint32_t ks2 = k0 ^ k1 ^ 0x1BD11BDAu;
#define TF_R(r) { x0 += x1; x1 = (x1 << (r)) | (x1 >> (32 - (r))); x1 ^= x0; }
  x0 += k0; x1 += k1;
  TF_R(13) TF_R(15) TF_R(26) TF_R(6)
  x0 += k1;  x1 += ks2 + 1u;
  TF_R(17) TF_R(29) TF_R(16) TF_R(24)
  x0 += ks2; x1 += k0 + 2u;
  TF_R(13) TF_R(15) TF_R(26) TF_R(6)
  x0 += k0;  x1 += k1 + 3u;
  TF_R(17) TF_R(29) TF_R(16) TF_R(24)
  x0 += k1;  x1 += ks2 + 4u;
  TF_R(13) TF_R(15) TF_R(26) TF_R(6)
  x0 += ks2; x1 += k0 + 5u;
#undef TF_R
  *o0 = x0; *o1 = x1;
}

__device__ static inline uint32_t mant_of(uint32_t k0, uint32_t k1, uint32_t n) {
  uint32_t o0, o1;
  tf2x32(k0, k1, 0u, n, &o0, &o1);   // partitionable: counter = (hi=0, lo=n)
  return (o0 ^ o1) >> 9;             // 23-bit mantissa
}

// IoU in the reference's exact fp32 op order (contraction OFF).
__device__ static inline float iou1(float a0, float a1, float a2, float a3,
                                    float aarea, float g0, float g1, float g2,
                                    float g3, float garea) {
  #pragma clang fp contract(off)
  float ix1 = fmaxf(a0, g0);
  float iy1 = fmaxf(a1, g1);
  float ix2 = fminf(a2, g2);
  float iy2 = fminf(a3, g3);
  float iw = ix2 - ix1 + 1.0f;
  float ih = iy2 - iy1 + 1.0f;
  float inter = (iw > 0.0f && ih > 0.0f) ? iw * ih : 0.0f;
  float den = aarea + garea - inter;
  return inter / den;                  // IEEE-rounded div
}

// ---- per-gt windowed max IoU (8 slices/gt); also zeroes ws ctrl region ----
__global__ __launch_bounds__(256) void k_gmax(const float* __restrict__ gt,
                                              const int* __restrict__ imw_p,
                                              const int* __restrict__ imh_p,
                                              uint32_t* __restrict__ ws) {
  #pragma clang fp contract(off)
  int tid = threadIdx.x;
  int b = blockIdx.x;
  int gid = b * 256 + tid;
  if (gid < NZ) ws[ZERO_BEG + gid] = 0u;   // folded k_init

  int g = b >> 3, sl = b & 7;
  float g0 = gt[g*4+0], g1 = gt[g*4+1], g2 = gt[g*4+2], g3 = gt[g*4+3];
  float gw = g2 - g0 + 1.0f, gh = g3 - g1 + 1.0f;
  float ga = (gw > 0.0f && gh > 0.0f) ? gw * gh : 0.0f;
  float imw = (float)imw_p[0], imh = (float)imh_p[0];

  float mx = 0.0f;   // g_max >= 0 always (some valid anchor exists)
  for (int a = 0; a < NUM_A; a++) {
    float b0 = BA[a][0], b1 = BA[a][1], b2 = BA[a][2], b3 = BA[a][3];
    int wlo = max(0,   (int)floorf((g0 - 1.0f - b2) * 0.0625f));
    int whi = min(255, (int)ceilf ((g2 + 1.0f - b0) * 0.0625f));
    int hlo = max(0,   (int)floorf((g1 - 1.0f - b3) * 0.0625f));
    int hhi = min(255, (int)ceilf ((g3 + 1.0f - b1) * 0.0625f));
    int wx = whi - wlo + 1, wy = hhi - hlo + 1;
    if (wx <= 0 || wy <= 0) continue;
    int tot = wx * wy;
    for (int idx = sl * 256 + tid; idx < tot; idx += 2048) {
      int h = hlo + idx / wx, w = wlo + idx % wx;
      float sx = (float)(w << 4), sy = (float)(h << 4);
      float x1 = b0 + sx, y1 = b1 + sy, x2 = b2 + sx, y2 = b3 + sy;
      float aw = x2 - x1 + 1.0f, ah = y2 - y1 + 1.0f;
      float aarea = aw * ah;
      bool vld = (x1 >= 0.0f) && (y1 >= 0.0f) && (x2 < imw) && (y2 < imh);
      float o = iou1(x1, y1, x2, y2, aarea, g0, g1, g2, g3, ga);
      if (vld) mx = fmaxf(mx, o);
    }
  }
  #pragma unroll
  for (int s = 32; s >= 1; s >>= 1) mx = fmaxf(mx, __shfl_xor(mx, s, 64));
  __shared__ float wmax[4];
  if ((tid & 63) == 0) wmax[tid >> 6] = mx;
  __syncthreads();
  if (tid == 0) {
    float m = fmaxf(fmaxf(wmax[0], wmax[1]), fmaxf(wmax[2], wmax[3]));
    ws[OFF_GMAX8 + g * 8 + sl] = __float_as_uint(m);
  }
}

// ---- main pass: 4 anchors/thread; labels/adj/mantissa/hist; last-block
// computes subsample boundaries (select) --------------------------------
__global__ __launch_bounds__(256) void k_main(const float* __restrict__ gt,
                                              const int* __restrict__ imw_p,
                                              const int* __restrict__ imh_p,
                                              float* __restrict__ out_adj,
                                              uint32_t* __restrict__ ws,
                                              uint32_t kf0, uint32_t kf1,
                                              uint32_t kb0, uint32_t kb1) {
  #pragma clang fp contract(off)
  __shared__ float sg0[NG], sg1[NG], sg2[NG], sg3[NG], sga[NG], sgm[NG];
  __shared__ uint32_t sh[2 * NBIN];
  __shared__ unsigned long long sMask[4];
  __shared__ int sAnyZero, sLast;
  int tid = threadIdx.x;
  {
    uint4* sh4 = (uint4*)sh;
    #pragma unroll
    for (int k = 0; k < 4; k++) sh4[tid + k * 256] = make_uint4(0, 0, 0, 0);
  }
  if (tid == 0) sAnyZero = 0;
  if (tid < NG) {
    const float4 g4 = ((const float4*)gt)[tid];
    sg0[tid] = g4.x; sg1[tid] = g4.y; sg2[tid] = g4.z; sg3[tid] = g4.w;
    float gw = g4.z - g4.x + 1.0f, gh = g4.w - g4.y + 1.0f;
    sga[tid] = (gw > 0.0f && gh > 0.0f) ? gw * gh : 0.0f;
    uint32_t mm = 0u;
    #pragma unroll
    for (int j = 0; j < 8; j++) mm = max(mm, ws[OFF_GMAX8 + tid * 8 + j]);
    sgm[tid] = __uint_as_float(mm);
    if (mm == 0u) atomicOr(&sAnyZero, 1);
  }
  __syncthreads();

  int b = blockIdx.x;
  int a = b >> 6, hb = (b & 63) << 2;      // anchor type, 4 rows hb..hb+3
  float BA0 = BA[a][0], BA1 = BA[a][1], BA2 = BA[a][2], BA3 = BA[a][3];

  // per-wave y-mask: wave r handles row hb+r; lane = gt index
  {
    int wv = tid >> 6, g = tid & 63;
    float sy = (float)((hb + wv) << 4);
    float ihp = fminf(BA3 + sy, sg3[g]) - fmaxf(BA1 + sy, sg1[g]) + 1.0f;
    unsigned long long mk = __ballot(ihp > 0.0f);
    if (g == 0) sMask[wv] = mk;
  }
  __syncthreads();

  float imw = (float)imw_p[0], imh = (float)imh_p[0];
  int w = tid;
  float sx = (float)(w << 4);
  float A0 = BA0 + sx, A2 = BA2 + sx;
  float aw = A2 - A0 + 1.0f;
  float A1v[4], A3v[4];
  #pragma unroll
  for (int r = 0; r < 4; r++) {
    float sy = (float)((hb + r) << 4);
    A1v[r] = BA1 + sy; A3v[r] = BA3 + sy;
  }
  float ah = A3v[0] - A1v[0] + 1.0f;
  float aarea = aw * ah;                   // exact ints -> bit-exact
  bool xv = (A0 >= 0.0f) && (A2 < imw);

  unsigned long long mk0 = sMask[0], mk1 = sMask[1],
                     mk2 = sMask[2], mk3 = sMask[3];
  unsigned long long uni = mk0 | mk1 | mk2 | mk3;
  float amaxv[4] = {0.f, 0.f, 0.f, 0.f};
  int bgv[4] = {0, 0, 0, 0};
  uint32_t afv = 0u;
  while (uni) {
    int g = __ffsll(uni) - 1;
    uni &= uni - 1;
    float iw = fminf(A2, sg2[g]) - fmaxf(A0, sg0[g]) + 1.0f;
    if (!__any(iw > 0.0f)) continue;
    if (iw > 0.0f) {
      float base = aarea + sga[g];
      float gy1 = sg1[g], gy2 = sg3[g], gm = sgm[g];
#define DO_ROW(r, mk)                                                     \
      if ((mk >> g) & 1ull) {                                             \
        float ih = fminf(A3v[r], gy2) - fmaxf(A1v[r], gy1) + 1.0f;        \
        float inter = iw * ih;                                            \
        float o = inter / (base - inter);                                 \
        if (o > amaxv[r]) { amaxv[r] = o; bgv[r] = g; }                   \
        if (o == gm) afv |= (1u << r);                                    \
      }
      DO_ROW(0, mk0) DO_ROW(1, mk1) DO_ROW(2, mk2) DO_ROW(3, mk3)
#undef DO_ROW
    }
  }

  bool anyZ = (sAnyZero != 0);
  #pragma unroll
  for (int r = 0; r < 4; r++) {
    int hw = (hb + r) * 256 + w;
    bool valid = xv && (A1v[r] >= 0.0f) && (A3v[r] < imh);
    float amax = amaxv[r];
    bool anyfg = (((afv >> r) & 1u) || anyZ) && valid;
    uint32_t lab;
    if (!valid)                       lab = LAB_IGN;
    else if (anyfg || amax >= 0.7f)   lab = LAB_FG;
    else if (amax < 0.3f)             lab = LAB_BG;
    else                              lab = LAB_IGN;

    float adj0 = 0.f, adj1 = 0.f, adj2 = 0.f, adj3 = 0.f;
    if (valid) {
      int bg = bgv[r];
      float G0 = sg0[bg], G1 = sg1[bg], G2 = sg2[bg], G3 = sg3[bg];
      float ax = (A2 + A0) * 0.5f, ay = (A3v[r] + A1v[r]) * 0.5f;
      float gwm = G2 - G0 + 1.0f, ghm = G3 - G1 + 1.0f;
      float gx = (G2 + G0) * 0.5f, gy = (G3 + G1) * 0.5f;
      adj0 = (gx - ax) / aw;
      adj1 = (gy - ay) / ah;
      adj2 = logf(gwm / aw);
      adj3 = logf(ghm / ah);
    }
    int c4 = a * 4;
    out_adj[(c4 + 0) * HW + hw] = adj0;
    out_adj[(c4 + 1) * HW + hw] = adj1;
    out_adj[(c4 + 2) * HW + hw] = adj2;
    out_adj[(c4 + 3) * HW + hw] = adj3;

    uint32_t m = 0u;
    uint32_t n = (uint32_t)(hw * 9 + a);   // original anchor index (tie-break)
    if (lab != LAB_IGN) {
      uint32_t kk0 = (lab == LAB_FG) ? kf0 : kb0;
      uint32_t kk1 = (lab == LAB_FG) ? kf1 : kb1;
      m = mant_of(kk0, kk1, n);
      atomicAdd(&sh[((lab == LAB_FG) ? 0 : NBIN) + (m >> BIN_SHIFT)], 1u);
    }
    ws[OFF_LABM + a * HW + hw] = (lab << 24) | m;
  }

  __syncthreads();
  for (int i = tid; i < 2 * NBIN; i += 256) {
    uint32_t v = sh[i];
    if (v) atomicAdd(&ws[OFF_HF + i], v);
  }
  __syncthreads();
  if (tid == 0)
    sLast = (atomicAdd(&ws[OFF_DONE2], 1u) == 575u) ? 1 : 0;
  __syncthreads();
  if (sLast) {
    // replicated k_select, reading global hist via device-scope atomic loads
    for (int cls = 0; cls < 2; cls++) {
      uint32_t* hist = ws + (cls ? OFF_HB : OFF_HF);
      uint32_t* sel = ws + OFF_SEL + cls * 4;
      uint32_t loc[8], s = 0;
      #pragma unroll
      for (int j = 0; j < 8; j++) {
        loc[j] = __hip_atomic_load(&hist[tid * 8 + j], __ATOMIC_RELAXED,
                                   __HIP_MEMORY_SCOPE_AGENT);
        s += loc[j];
      }
      sh[tid] = s; __syncthreads();
      for (int off = 1; off < 256; off <<= 1) {
        uint32_t v = (tid >= off) ? sh[tid - off] : 0u;
        __syncthreads();
        sh[tid] += v;
        __syncthreads();
      }
      uint32_t total = sh[255];
      uint32_t K = total < CAPK ? total : CAPK;
      if (tid == 0) {
        sel[3] = K;
        if (K == 0u) { sel[0] = 0xFFFFFFFFu; sel[1] = 0u; sel[2] = 0u; }
      }
      if (K > 0u) {
        uint32_t myC = sh[tid], pvC = (tid == 0) ? 0u : sh[tid - 1];
        if (myC >= K && pvC < K) {
          uint32_t cum = pvC; int bb = tid * 8;
          for (int j = 0; j < 8; j++) {
            if (cum + loc[j] >= K) { bb = tid * 8 + j; break; }
            cum += loc[j];
          }
          sel[0] = (uint32_t)bb; sel[1] = cum; sel[2] = K - cum;
        }
      }
      __syncthreads();
    }
  }
}

// ---- emit labels + wts; boundary-bin anchors -> candidate lists -----------
__global__ __launch_bounds__(256) void k_emit(float* __restrict__ out_lab,
                                              float* __restrict__ out_wts,
                                              uint32_t* __restrict__ ws) {
  int t = blockIdx.x * 256 + threadIdx.x;
  uint32_t lm = ws[OFF_LABM + t];
  uint32_t lab = lm >> 24;
  uint32_t m = lm & 0x7FFFFFu;
  uint32_t Kf = ws[OFF_SEL + 3], Kb = ws[OFF_SEL + 7];
  float inv = 1.0f / (float)(Kf + Kb);   // 1/num_ni
  int a = t >> 16, hw = t & 65535;
  uint32_t n = (uint32_t)(hw * 9 + a);

  float outv = 2.0f, wv = 0.0f;
  if (lab == LAB_FG) {
    uint32_t b = m >> BIN_SHIFT, bf = ws[OFF_SEL + 0];
    if (b < bf) { outv = 1.0f; wv = inv; }
    else if (b == bf) {
      uint32_t idx = atomicAdd(&ws[OFF_CNTF], 1u);
      if (idx < CAND_CAP)
        ((uint64_t*)(ws + OFF_CANDF))[idx] = ((uint64_t)m << 20) | (uint64_t)n;
    }
  } else if (lab == LAB_BG) {
    uint32_t b = m >> BIN_SHIFT, bb = ws[OFF_SEL + 4];
    if (b < bb) { outv = 0.0f; }
    else if (b == bb) {
      uint32_t idx = atomicAdd(&ws[OFF_CNTB], 1u);
      if (idx < CAND_CAP)
        ((uint64_t*)(ws + OFF_CANDB))[idx] = ((uint64_t)m << 20) | (uint64_t)n;
    }
  }
  out_lab[t] = outv;
  int c4 = a * 4;
  out_wts[(c4 + 0) * HW + hw] = wv;
  out_wts[(c4 + 1) * HW + hw] = wv;
  out_wts[(c4 + 2) * HW + hw] = wv;
  out_wts[(c4 + 3) * HW + hw] = wv;
}

// ---- rank boundary candidates (staged in LDS); promote rank < need --------
__global__ __launch_bounds__(256) void k_fixup(float* __restrict__ out_lab,
                                               float* __restrict__ out_wts,
                                               uint32_t* __restrict__ ws) {
  __shared__ uint64_t sc[CAND_CAP];        // 32 KB
  int cls = blockIdx.x;
  uint32_t cnt = ws[cls == 0 ? OFF_CNTF : OFF_CNTB];
  uint32_t C = cnt < CAND_CAP ? cnt : CAND_CAP;
  uint32_t need = ws[OFF_SEL + cls * 4 + 2];
  uint32_t Kf = ws[OFF_SEL + 3], Kb = ws[OFF_SEL + 7];
  float inv = 1.0f / (float)(Kf + Kb);
  const uint64_t* cand =
      (const uint64_t*)(ws + (cls == 0 ? OFF_CANDF : OFF_CANDB));
  for (uint32_t i = threadIdx.x; i < C; i += 256) sc[i] = cand[i];
  __syncthreads();
  for (uint32_t i = threadIdx.x; i < C; i += 256) {
    uint64_t k = sc[i];
    uint32_t r = 0;
    for (uint32_t j = 0; j < C; j++) r += (sc[j] < k) ? 1u : 0u;
    if (r < need) {                      // keys unique -> exactly `need` kept
      uint32_t n = (uint32_t)(k & 0xFFFFFu);
      uint32_t a = n % 9u, hw = n / 9u;
      uint32_t t = a * HW + hw;
      if (cls == 0) {
        out_lab[t] = 1.0f;
        #pragma unroll
        for (int j = 0; j < 4; j++) out_wts[(a * 4 + j) * HW + hw] = inv;
      } else {
        out_lab[t] = 0.0f;
      }
    }
  }
}

extern "C" void kernel_launch(void* const* d_in, const int* in_sizes, int n_in,
                              void* d_out, int out_size, void* d_ws,
                              size_t ws_size, hipStream_t stream) {
  const float* gt  = (const float*)d_in[1];
  const int*   imw = (const int*)d_in[2];
  const int*   imh = (const int*)d_in[3];
  float* out      = (float*)d_out;
  float* out_lab  = out;                   // 589824
  float* out_adj  = out + N_ANCH;          // 4*589824
  float* out_wts  = out + 5 * N_ANCH;      // 4*589824
  uint32_t* ws = (uint32_t*)d_ws;          // ~2.44 MB used

  uint32_t kf0, kf1, kb0, kb1;
  tf2x32(0u, 42u, 0u, 0u, &kf0, &kf1);
  tf2x32(0u, 42u, 0u, 1u, &kb0, &kb1);

  hipLaunchKernelGGL(k_gmax, dim3(NG * 8), dim3(256), 0, stream, gt, imw, imh,
                     ws);
  hipLaunchKernelGGL(k_main, dim3(576), dim3(256), 0, stream, gt, imw, imh,
                     out_adj, ws, kf0, kf1, kb0, kb1);
  hipLaunchKernelGGL(k_emit, dim3(N_ANCH / 256), dim3(256), 0, stream, out_lab,
                     out_wts, ws);
  hipLaunchKernelGGL(k_fixup, dim3(2), dim3(256), 0, stream, out_lab, out_wts,
                     ws);
}